// Round 20
// baseline (308.112 us; speedup 1.0000x reference)
//
#include <hip/hip_runtime.h>

#define DIM 64
#define PBITS 6
#define PART_BUCKETS 64       // buckets per partition
#define NPART_MAX 2368        // >= ceil(150016/64)=2344
#define EPB 8192              // edges per block, pass1 (1024 threads x 2 x int4)
#define CAPE 2944             // slot capacity, entity partitions (avg 2560, +7.6 sigma)
#define CAPU 1664             // slot capacity, user partitions (avg 1280, +10.7 sigma)
#define RECK ((CAPE + 255) / 256)

typedef float f4nt __attribute__((ext_vector_type(4)));
typedef unsigned long long u64;

__device__ __forceinline__ void nt_store_rec(uint2* dst, unsigned meta, unsigned vb) {
    __builtin_nontemporal_store(((u64)vb << 32) | (u64)meta, (u64*)dst);
}
__device__ __forceinline__ uint2 nt_load_rec(const uint2* src) {
    u64 u = __builtin_nontemporal_load((const u64*)src);
    return make_uint2((unsigned)u, (unsigned)(u >> 32));
}

// ---------------- fallback (round-1) atomic kernel ----------------
__global__ void coo_scatter_kernel(const float* __restrict__ user_emb,
                                   const float* __restrict__ entity_emb,
                                   const int* __restrict__ rows,
                                   const int* __restrict__ cols,
                                   const float* __restrict__ vals,
                                   float* __restrict__ entity_agg,
                                   float* __restrict__ user_agg,
                                   int nnz) {
    long long tid = (long long)blockIdx.x * blockDim.x + threadIdx.x;
    long long total = (long long)nnz * DIM;
    if (tid >= total) return;
    int edge = (int)(tid >> 6);
    int d = (int)(tid & 63);
    int r = rows[edge];
    int c = cols[edge];
    float v = vals[edge];
    atomicAdd(&entity_agg[c * DIM + d], v * user_emb[r * DIM + d]);
    atomicAdd(&user_agg[r * DIM + d], v * entity_emb[c * DIM + d]);
}

// record: uint2 { meta, valbits }; meta = (local6<<18) | (side<<17) | src
// bucket = partition*64 + local6. side 0: gather user_emb; side 1: entity_emb.
// Static payload layout: partition p owns slots [slotbase(p), slotbase(p)+slotcap(p)).

__device__ __forceinline__ size_t slotbase(int p, int npeC) {
    return (p < npeC) ? (size_t)p * CAPE
                      : (size_t)npeC * CAPE + (size_t)(p - npeC) * CAPU;
}
__device__ __forceinline__ int slotcap(int p, int npeC) {
    return (p < npeC) ? CAPE : CAPU;
}

// pass1: edges cached in registers across both sweeps. Sweep A: LDS histogram.
// Claim one contiguous chunk per (block, partition). Sweep B: build records
// from registers, nontemporal-store at rank (payload is write-once).
__global__ __launch_bounds__(1024) void pass1_part(const int* __restrict__ rows,
                                                   const int* __restrict__ cols,
                                                   const float* __restrict__ vals,
                                                   int* __restrict__ cnt,
                                                   uint2* __restrict__ payload,
                                                   int ne, int nnz, int npart, int npeC) {
    __shared__ int hist[NPART_MAX];
    __shared__ int cur[NPART_MAX];
    for (int t = threadIdx.x; t < npart; t += 1024) hist[t] = 0;
    __syncthreads();

    int base = blockIdx.x * EPB;
    int4 c4[2], r4[2];
    float4 v4[2];

#pragma unroll
    for (int half = 0; half < 2; ++half) {
        int i0 = base + half * 4096 + threadIdx.x * 4;
        if (i0 + 3 < nnz) {
            c4[half] = *(const int4*)(cols + i0);
            r4[half] = *(const int4*)(rows + i0);
            v4[half] = *(const float4*)(vals + i0);
        } else {
            int* cc = (int*)&c4[half];
            int* rr = (int*)&r4[half];
            float* vv = (float*)&v4[half];
#pragma unroll
            for (int j = 0; j < 4; ++j) {
                int i = i0 + j;
                cc[j] = (i < nnz) ? cols[i] : -1;
                rr[j] = (i < nnz) ? rows[i] : 0;
                vv[j] = (i < nnz) ? vals[i] : 0.f;
            }
        }
        int* cc = (int*)&c4[half];
        int* rr = (int*)&r4[half];
#pragma unroll
        for (int j = 0; j < 4; ++j) {
            if (cc[j] >= 0) {
                atomicAdd(&hist[cc[j] >> PBITS], 1);
                atomicAdd(&hist[(ne + rr[j]) >> PBITS], 1);
            }
        }
    }
    __syncthreads();
    for (int p = threadIdx.x; p < npart; p += 1024) {
        int c_ = hist[p];
        cur[p] = c_ ? atomicAdd(&cnt[p], c_) : 0;
    }
    __syncthreads();

#pragma unroll
    for (int half = 0; half < 2; ++half) {
        int* cc = (int*)&c4[half];
        int* rr = (int*)&r4[half];
        float* vv = (float*)&v4[half];
#pragma unroll
        for (int j = 0; j < 4; ++j) {
            int c = cc[j];
            if (c >= 0) {
                int r = rr[j];
                unsigned vb = __float_as_uint(vv[j]);
                int b2 = ne + r;
                int p1 = c >> PBITS;
                int p2 = b2 >> PBITS;
                int s1 = atomicAdd(&cur[p1], 1);
                if (s1 < slotcap(p1, npeC))
                    nt_store_rec(&payload[slotbase(p1, npeC) + s1],
                                 ((unsigned)(c & (PART_BUCKETS - 1)) << 18) | (unsigned)r, vb);
                int s2 = atomicAdd(&cur[p2], 1);
                if (s2 < slotcap(p2, npeC))
                    nt_store_rec(&payload[slotbase(p2, npeC) + s2],
                                 ((unsigned)(b2 & (PART_BUCKETS - 1)) << 18) | (1u << 17) | (unsigned)c, vb);
            }
        }
    }
}

// fused sort+agg: one block per partition. Load records (nontemporal) to regs,
// counting sort into LDS, then each wave aggregates 16 buckets from LDS.
// Random 256B-row gather runs at ~3.5 TB/s (pattern ceiling; measured
// occupancy- and element-width-independent across r11-r18).
__global__ __launch_bounds__(256) void sort_agg(const float* __restrict__ user_emb,
                                                const float* __restrict__ entity_emb,
                                                const uint2* __restrict__ payload,
                                                const int* __restrict__ cnt,
                                                int* __restrict__ ovfcnt,
                                                unsigned char* __restrict__ ovfflag,
                                                float* __restrict__ out,
                                                int nb, int npeC) {
    __shared__ uint2 srec[CAPE];                      // 23 KB sorted records
    __shared__ int h[PART_BUCKETS], sc[PART_BUCKETS], cu[PART_BUCKETS];
    int p = blockIdx.x;
    size_t beg = slotbase(p, npeC);
    int cap = slotcap(p, npeC);
    int n = cnt[p];
    int t = threadIdx.x;
    if (t < PART_BUCKETS) h[t] = 0;
    __syncthreads();

    if (n > cap) {   // ~8-10 sigma; zero rows, defer to rescan atomics
        if (t == 0) {
            atomicAdd(ovfcnt, 1);
            ovfflag[p] = 1;
        }
        int b0 = p << PBITS;
        for (int e = t; e < PART_BUCKETS * DIM; e += 256) {
            int b = b0 + (e >> 6);
            if (b < nb) out[(size_t)b * DIM + (e & 63)] = 0.f;
        }
        return;
    }

    uint2 rec[RECK];
#pragma unroll
    for (int k = 0; k < RECK; ++k) {
        int idx = t + k * 256;
        if (idx < n) {
            rec[k] = nt_load_rec(&payload[beg + idx]);
            atomicAdd(&h[(rec[k].x >> 18) & (PART_BUCKETS - 1)], 1);
        }
    }
    __syncthreads();
    if (t == 0) {
        int run = 0;
#pragma unroll
        for (int j = 0; j < PART_BUCKETS; ++j) { sc[j] = run; cu[j] = run; run += h[j]; }
    }
    __syncthreads();
#pragma unroll
    for (int k = 0; k < RECK; ++k) {
        int idx = t + k * 256;
        if (idx < n) {
            int b = (rec[k].x >> 18) & (PART_BUCKETS - 1);
            int rank = atomicAdd(&cu[b], 1);
            srec[rank] = rec[k];
        }
    }
    __syncthreads();

    // phase 2: wave w aggregates buckets [w*16, w*16+16)
    int wid = t >> 6;
    int lane = t & 63;
    int grp = lane >> 4;      // which record of the quad
    int sub = lane & 15;      // float4 slot within the row

    for (int bi = 0; bi < 16; ++bi) {
        int lb = wid * 16 + bi;
        int bucket = (p << PBITS) + lb;
        int rb = sc[lb];
        int cntb = h[lb];

        float ax0 = 0.f, ay0 = 0.f, az0 = 0.f, aw0 = 0.f;
        float ax1 = 0.f, ay1 = 0.f, az1 = 0.f, aw1 = 0.f;
        float ax2 = 0.f, ay2 = 0.f, az2 = 0.f, aw2 = 0.f;
        float ax3 = 0.f, ay3 = 0.f, az3 = 0.f, aw3 = 0.f;

        int i = 0;
        for (; i + 16 <= cntb; i += 16) {
            uint2 r0 = srec[rb + i + grp];
            uint2 r1 = srec[rb + i + 4 + grp];
            uint2 r2 = srec[rb + i + 8 + grp];
            uint2 r3 = srec[rb + i + 12 + grp];
            const float* __restrict__ t0 = (r0.x & (1u << 17)) ? entity_emb : user_emb;
            const float* __restrict__ t1 = (r1.x & (1u << 17)) ? entity_emb : user_emb;
            const float* __restrict__ t2 = (r2.x & (1u << 17)) ? entity_emb : user_emb;
            const float* __restrict__ t3 = (r3.x & (1u << 17)) ? entity_emb : user_emb;
            const float4 e0 = *(const float4*)(t0 + (size_t)(r0.x & 0x1FFFFu) * DIM + sub * 4);
            const float4 e1 = *(const float4*)(t1 + (size_t)(r1.x & 0x1FFFFu) * DIM + sub * 4);
            const float4 e2 = *(const float4*)(t2 + (size_t)(r2.x & 0x1FFFFu) * DIM + sub * 4);
            const float4 e3 = *(const float4*)(t3 + (size_t)(r3.x & 0x1FFFFu) * DIM + sub * 4);
            float v0 = __uint_as_float(r0.y);
            float v1 = __uint_as_float(r1.y);
            float v2 = __uint_as_float(r2.y);
            float v3 = __uint_as_float(r3.y);
            ax0 += v0 * e0.x; ay0 += v0 * e0.y; az0 += v0 * e0.z; aw0 += v0 * e0.w;
            ax1 += v1 * e1.x; ay1 += v1 * e1.y; az1 += v1 * e1.z; aw1 += v1 * e1.w;
            ax2 += v2 * e2.x; ay2 += v2 * e2.y; az2 += v2 * e2.z; aw2 += v2 * e2.w;
            ax3 += v3 * e3.x; ay3 += v3 * e3.y; az3 += v3 * e3.z; aw3 += v3 * e3.w;
        }
        for (; i + 8 <= cntb; i += 8) {
            uint2 rA = srec[rb + i + grp];
            uint2 rB = srec[rb + i + 4 + grp];
            const float* __restrict__ tA = (rA.x & (1u << 17)) ? entity_emb : user_emb;
            const float* __restrict__ tB = (rB.x & (1u << 17)) ? entity_emb : user_emb;
            const float4 eA = *(const float4*)(tA + (size_t)(rA.x & 0x1FFFFu) * DIM + sub * 4);
            const float4 eB = *(const float4*)(tB + (size_t)(rB.x & 0x1FFFFu) * DIM + sub * 4);
            float vA = __uint_as_float(rA.y);
            float vB = __uint_as_float(rB.y);
            ax0 += vA * eA.x; ay0 += vA * eA.y; az0 += vA * eA.z; aw0 += vA * eA.w;
            ax1 += vB * eB.x; ay1 += vB * eB.y; az1 += vB * eB.z; aw1 += vB * eB.w;
        }
        for (; i < cntb; i += 4) {
            int j = i + grp;
            bool valid = j < cntb;
            uint2 r = srec[rb + (valid ? j : cntb - 1)];
            const float* __restrict__ tb = (r.x & (1u << 17)) ? entity_emb : user_emb;
            const float4 e = *(const float4*)(tb + (size_t)(r.x & 0x1FFFFu) * DIM + sub * 4);
            float v = valid ? __uint_as_float(r.y) : 0.f;
            ax0 += v * e.x; ay0 += v * e.y; az0 += v * e.z; aw0 += v * e.w;
        }

        ax0 += ax1 + ax2 + ax3; ay0 += ay1 + ay2 + ay3;
        az0 += az1 + az2 + az3; aw0 += aw1 + aw2 + aw3;
        ax0 += __shfl_xor(ax0, 16, 64); ay0 += __shfl_xor(ay0, 16, 64);
        az0 += __shfl_xor(az0, 16, 64); aw0 += __shfl_xor(aw0, 16, 64);
        ax0 += __shfl_xor(ax0, 32, 64); ay0 += __shfl_xor(ay0, 32, 64);
        az0 += __shfl_xor(az0, 32, 64); aw0 += __shfl_xor(aw0, 32, 64);

        if (grp == 0 && bucket < nb) {
            f4nt res = {ax0, ay0, az0, aw0};
            __builtin_nontemporal_store(res, (f4nt*)(out + (size_t)bucket * DIM + sub * 4));
        }
    }
}

// rescan: reapply edges of overflowed partitions via atomics (normally no-op)
__global__ void pass3_rescan(const int* __restrict__ rows,
                             const int* __restrict__ cols,
                             const float* __restrict__ vals,
                             const float* __restrict__ user_emb,
                             const float* __restrict__ entity_emb,
                             const int* __restrict__ ovfcnt,
                             const unsigned char* __restrict__ ovfflag,
                             float* __restrict__ out, int ne, int nnz) {
    if (*ovfcnt == 0) return;
    for (int i = blockIdx.x * blockDim.x + threadIdx.x; i < nnz;
         i += gridDim.x * blockDim.x) {
        int c = cols[i];
        int r = rows[i];
        float v = vals[i];
        if (ovfflag[c >> PBITS]) {
            const float* src = user_emb + (size_t)r * DIM;
            float* dst = out + (size_t)c * DIM;
            for (int d = 0; d < DIM; ++d) atomicAdd(&dst[d], v * src[d]);
        }
        int b2 = ne + r;
        if (ovfflag[b2 >> PBITS]) {
            const float* src = entity_emb + (size_t)c * DIM;
            float* dst = out + (size_t)b2 * DIM;
            for (int d = 0; d < DIM; ++d) atomicAdd(&dst[d], v * src[d]);
        }
    }
}

extern "C" void kernel_launch(void* const* d_in, const int* in_sizes, int n_in,
                              void* d_out, int out_size, void* d_ws, size_t ws_size,
                              hipStream_t stream) {
    const float* user_emb   = (const float*)d_in[0];  // [n_users, 64]
    const float* entity_emb = (const float*)d_in[1];  // [n_entities, 64]
    const int*   rows       = (const int*)d_in[2];
    const int*   cols       = (const int*)d_in[3];
    const float* vals       = (const float*)d_in[4];
    int nnz = in_sizes[2];
    int nu  = in_sizes[0] / DIM;   // 100000
    int ne  = in_sizes[1] / DIM;   // 50000
    int nb  = ne + nu;             // 150000 buckets
    int npart = (nb + PART_BUCKETS - 1) >> PBITS;   // 2344
    int npeC  = (ne + PART_BUCKETS - 1) >> PBITS;   // 782 (entity + straddle)

    float* out = (float*)d_out;

    // ws layout: cnt[npart] int | ovfcnt int | ovfflag[npart] bytes | pad | payload
    size_t meta_bytes = (size_t)npart * 4 + 4 + (size_t)npart;
    size_t pay_off = (meta_bytes + 15) & ~(size_t)15;
    size_t nslots = (size_t)npeC * CAPE + (size_t)(npart - npeC) * CAPU;
    size_t need = pay_off + nslots * 8;
    long long avg_e = (long long)nnz * PART_BUCKETS / (ne > 0 ? ne : 1);
    long long avg_u = (long long)nnz * PART_BUCKETS / (nu > 0 ? nu : 1);

    if (ws_size < need || npart > NPART_MAX || nu > 131072 || ne > 131072 ||
        avg_e > 2700 || avg_u > 1500) {
        float* entity_agg = out;
        float* user_agg   = out + (size_t)ne * DIM;
        hipMemsetAsync(d_out, 0, (size_t)out_size * sizeof(float), stream);
        long long total = (long long)nnz * DIM;
        int block = 256;
        long long grid = (total + block - 1) / block;
        coo_scatter_kernel<<<(int)grid, block, 0, stream>>>(
            user_emb, entity_emb, rows, cols, vals, entity_agg, user_agg, nnz);
        return;
    }

    int*           cnt     = (int*)d_ws;
    int*           ovfcnt  = cnt + npart;
    unsigned char* ovfflag = (unsigned char*)(ovfcnt + 1);
    uint2*         payload = (uint2*)((char*)d_ws + pay_off);

    hipMemsetAsync(d_ws, 0, meta_bytes, stream);

    int g1 = (nnz + EPB - 1) / EPB;
    pass1_part<<<g1, 1024, 0, stream>>>(rows, cols, vals, cnt, payload, ne, nnz, npart, npeC);
    sort_agg<<<npart, 256, 0, stream>>>(user_emb, entity_emb, payload, cnt,
                                        ovfcnt, ovfflag, out, nb, npeC);
    pass3_rescan<<<512, 256, 0, stream>>>(rows, cols, vals, user_emb, entity_emb,
                                          ovfcnt, ovfflag, out, ne, nnz);
}

// Round 21
// 201.944 us; speedup vs baseline: 1.5257x; 1.5257x over previous
//
#include <hip/hip_runtime.h>

#define DIM 64
#define PBITS 6
#define PART_BUCKETS 64       // buckets per partition
#define NPART_MAX 2368        // >= ceil(150016/64)=2344
#define EPB 8192              // edges per block, pass1 (1024 threads x 2 x int4)
#define CAPE 2944             // slot capacity, entity partitions (avg 2560, +7.6 sigma)
#define CAPU 1664             // slot capacity, user partitions (avg 1280, +10.7 sigma)
#define RECK ((CAPE + 255) / 256)

// ---------------- fallback (round-1) atomic kernel ----------------
__global__ void coo_scatter_kernel(const float* __restrict__ user_emb,
                                   const float* __restrict__ entity_emb,
                                   const int* __restrict__ rows,
                                   const int* __restrict__ cols,
                                   const float* __restrict__ vals,
                                   float* __restrict__ entity_agg,
                                   float* __restrict__ user_agg,
                                   int nnz) {
    long long tid = (long long)blockIdx.x * blockDim.x + threadIdx.x;
    long long total = (long long)nnz * DIM;
    if (tid >= total) return;
    int edge = (int)(tid >> 6);
    int d = (int)(tid & 63);
    int r = rows[edge];
    int c = cols[edge];
    float v = vals[edge];
    atomicAdd(&entity_agg[c * DIM + d], v * user_emb[r * DIM + d]);
    atomicAdd(&user_agg[r * DIM + d], v * entity_emb[c * DIM + d]);
}

// record: uint2 { meta, valbits }; meta = (local6<<18) | (side<<17) | src
// bucket = partition*64 + local6. side 0: gather user_emb; side 1: entity_emb.
// Static payload layout: partition p owns slots [slotbase(p), slotbase(p)+slotcap(p)).
// NOTE (r20 lesson): payload stores MUST be regular (L2 write-back) stores —
// nontemporal hints bypass L2 line aggregation and resurrect the 8x
// partial-line write amplification (pass1 50 -> 163 us).

__device__ __forceinline__ size_t slotbase(int p, int npeC) {
    return (p < npeC) ? (size_t)p * CAPE
                      : (size_t)npeC * CAPE + (size_t)(p - npeC) * CAPU;
}
__device__ __forceinline__ int slotcap(int p, int npeC) {
    return (p < npeC) ? CAPE : CAPU;
}

// pass1: edges cached in registers across both sweeps. Sweep A: LDS histogram.
// Claim one contiguous chunk per (block, partition). Sweep B: build records
// from registers and store at rank.
__global__ __launch_bounds__(1024) void pass1_part(const int* __restrict__ rows,
                                                   const int* __restrict__ cols,
                                                   const float* __restrict__ vals,
                                                   int* __restrict__ cnt,
                                                   uint2* __restrict__ payload,
                                                   int ne, int nnz, int npart, int npeC) {
    __shared__ int hist[NPART_MAX];
    __shared__ int cur[NPART_MAX];
    for (int t = threadIdx.x; t < npart; t += 1024) hist[t] = 0;
    __syncthreads();

    int base = blockIdx.x * EPB;
    int4 c4[2], r4[2];
    float4 v4[2];

#pragma unroll
    for (int half = 0; half < 2; ++half) {
        int i0 = base + half * 4096 + threadIdx.x * 4;
        if (i0 + 3 < nnz) {
            c4[half] = *(const int4*)(cols + i0);
            r4[half] = *(const int4*)(rows + i0);
            v4[half] = *(const float4*)(vals + i0);
        } else {
            int* cc = (int*)&c4[half];
            int* rr = (int*)&r4[half];
            float* vv = (float*)&v4[half];
#pragma unroll
            for (int j = 0; j < 4; ++j) {
                int i = i0 + j;
                cc[j] = (i < nnz) ? cols[i] : -1;
                rr[j] = (i < nnz) ? rows[i] : 0;
                vv[j] = (i < nnz) ? vals[i] : 0.f;
            }
        }
        int* cc = (int*)&c4[half];
        int* rr = (int*)&r4[half];
#pragma unroll
        for (int j = 0; j < 4; ++j) {
            if (cc[j] >= 0) {
                atomicAdd(&hist[cc[j] >> PBITS], 1);
                atomicAdd(&hist[(ne + rr[j]) >> PBITS], 1);
            }
        }
    }
    __syncthreads();
    for (int p = threadIdx.x; p < npart; p += 1024) {
        int c_ = hist[p];
        cur[p] = c_ ? atomicAdd(&cnt[p], c_) : 0;
    }
    __syncthreads();

#pragma unroll
    for (int half = 0; half < 2; ++half) {
        int* cc = (int*)&c4[half];
        int* rr = (int*)&r4[half];
        float* vv = (float*)&v4[half];
#pragma unroll
        for (int j = 0; j < 4; ++j) {
            int c = cc[j];
            if (c >= 0) {
                int r = rr[j];
                unsigned vb = __float_as_uint(vv[j]);
                int b2 = ne + r;
                int p1 = c >> PBITS;
                int p2 = b2 >> PBITS;
                int s1 = atomicAdd(&cur[p1], 1);
                if (s1 < slotcap(p1, npeC))
                    payload[slotbase(p1, npeC) + s1] =
                        make_uint2(((unsigned)(c & (PART_BUCKETS - 1)) << 18) | (unsigned)r, vb);
                int s2 = atomicAdd(&cur[p2], 1);
                if (s2 < slotcap(p2, npeC))
                    payload[slotbase(p2, npeC) + s2] =
                        make_uint2(((unsigned)(b2 & (PART_BUCKETS - 1)) << 18) | (1u << 17) | (unsigned)c, vb);
            }
        }
    }
}

// fused sort+agg: one block per partition. Load records to regs, counting
// sort into LDS, then each wave aggregates 16 buckets straight from LDS.
// Random 256B-row gather runs at ~3.5 TB/s (pattern ceiling; measured
// occupancy- and element-width-independent across r11-r18).
__global__ __launch_bounds__(256) void sort_agg(const float* __restrict__ user_emb,
                                                const float* __restrict__ entity_emb,
                                                const uint2* __restrict__ payload,
                                                const int* __restrict__ cnt,
                                                int* __restrict__ ovfcnt,
                                                unsigned char* __restrict__ ovfflag,
                                                float* __restrict__ out,
                                                int nb, int npeC) {
    __shared__ uint2 srec[CAPE];                      // 23 KB sorted records
    __shared__ int h[PART_BUCKETS], sc[PART_BUCKETS], cu[PART_BUCKETS];
    int p = blockIdx.x;
    size_t beg = slotbase(p, npeC);
    int cap = slotcap(p, npeC);
    int n = cnt[p];
    int t = threadIdx.x;
    if (t < PART_BUCKETS) h[t] = 0;
    __syncthreads();

    if (n > cap) {   // ~8-10 sigma; zero rows, defer to rescan atomics
        if (t == 0) {
            atomicAdd(ovfcnt, 1);
            ovfflag[p] = 1;
        }
        int b0 = p << PBITS;
        for (int e = t; e < PART_BUCKETS * DIM; e += 256) {
            int b = b0 + (e >> 6);
            if (b < nb) out[(size_t)b * DIM + (e & 63)] = 0.f;
        }
        return;
    }

    uint2 rec[RECK];
#pragma unroll
    for (int k = 0; k < RECK; ++k) {
        int idx = t + k * 256;
        if (idx < n) {
            rec[k] = payload[beg + idx];
            atomicAdd(&h[(rec[k].x >> 18) & (PART_BUCKETS - 1)], 1);
        }
    }
    __syncthreads();
    if (t == 0) {
        int run = 0;
#pragma unroll
        for (int j = 0; j < PART_BUCKETS; ++j) { sc[j] = run; cu[j] = run; run += h[j]; }
    }
    __syncthreads();
#pragma unroll
    for (int k = 0; k < RECK; ++k) {
        int idx = t + k * 256;
        if (idx < n) {
            int b = (rec[k].x >> 18) & (PART_BUCKETS - 1);
            int rank = atomicAdd(&cu[b], 1);
            srec[rank] = rec[k];
        }
    }
    __syncthreads();

    // phase 2: wave w aggregates buckets [w*16, w*16+16)
    int wid = t >> 6;
    int lane = t & 63;
    int grp = lane >> 4;      // which record of the quad
    int sub = lane & 15;      // float4 slot within the row

    for (int bi = 0; bi < 16; ++bi) {
        int lb = wid * 16 + bi;
        int bucket = (p << PBITS) + lb;
        int rb = sc[lb];
        int cntb = h[lb];

        float ax0 = 0.f, ay0 = 0.f, az0 = 0.f, aw0 = 0.f;
        float ax1 = 0.f, ay1 = 0.f, az1 = 0.f, aw1 = 0.f;
        float ax2 = 0.f, ay2 = 0.f, az2 = 0.f, aw2 = 0.f;
        float ax3 = 0.f, ay3 = 0.f, az3 = 0.f, aw3 = 0.f;

        int i = 0;
        for (; i + 16 <= cntb; i += 16) {
            uint2 r0 = srec[rb + i + grp];
            uint2 r1 = srec[rb + i + 4 + grp];
            uint2 r2 = srec[rb + i + 8 + grp];
            uint2 r3 = srec[rb + i + 12 + grp];
            const float* __restrict__ t0 = (r0.x & (1u << 17)) ? entity_emb : user_emb;
            const float* __restrict__ t1 = (r1.x & (1u << 17)) ? entity_emb : user_emb;
            const float* __restrict__ t2 = (r2.x & (1u << 17)) ? entity_emb : user_emb;
            const float* __restrict__ t3 = (r3.x & (1u << 17)) ? entity_emb : user_emb;
            const float4 e0 = *(const float4*)(t0 + (size_t)(r0.x & 0x1FFFFu) * DIM + sub * 4);
            const float4 e1 = *(const float4*)(t1 + (size_t)(r1.x & 0x1FFFFu) * DIM + sub * 4);
            const float4 e2 = *(const float4*)(t2 + (size_t)(r2.x & 0x1FFFFu) * DIM + sub * 4);
            const float4 e3 = *(const float4*)(t3 + (size_t)(r3.x & 0x1FFFFu) * DIM + sub * 4);
            float v0 = __uint_as_float(r0.y);
            float v1 = __uint_as_float(r1.y);
            float v2 = __uint_as_float(r2.y);
            float v3 = __uint_as_float(r3.y);
            ax0 += v0 * e0.x; ay0 += v0 * e0.y; az0 += v0 * e0.z; aw0 += v0 * e0.w;
            ax1 += v1 * e1.x; ay1 += v1 * e1.y; az1 += v1 * e1.z; aw1 += v1 * e1.w;
            ax2 += v2 * e2.x; ay2 += v2 * e2.y; az2 += v2 * e2.z; aw2 += v2 * e2.w;
            ax3 += v3 * e3.x; ay3 += v3 * e3.y; az3 += v3 * e3.z; aw3 += v3 * e3.w;
        }
        for (; i + 8 <= cntb; i += 8) {
            uint2 rA = srec[rb + i + grp];
            uint2 rB = srec[rb + i + 4 + grp];
            const float* __restrict__ tA = (rA.x & (1u << 17)) ? entity_emb : user_emb;
            const float* __restrict__ tB = (rB.x & (1u << 17)) ? entity_emb : user_emb;
            const float4 eA = *(const float4*)(tA + (size_t)(rA.x & 0x1FFFFu) * DIM + sub * 4);
            const float4 eB = *(const float4*)(tB + (size_t)(rB.x & 0x1FFFFu) * DIM + sub * 4);
            float vA = __uint_as_float(rA.y);
            float vB = __uint_as_float(rB.y);
            ax0 += vA * eA.x; ay0 += vA * eA.y; az0 += vA * eA.z; aw0 += vA * eA.w;
            ax1 += vB * eB.x; ay1 += vB * eB.y; az1 += vB * eB.z; aw1 += vB * eB.w;
        }
        for (; i < cntb; i += 4) {
            int j = i + grp;
            bool valid = j < cntb;
            uint2 r = srec[rb + (valid ? j : cntb - 1)];
            const float* __restrict__ tb = (r.x & (1u << 17)) ? entity_emb : user_emb;
            const float4 e = *(const float4*)(tb + (size_t)(r.x & 0x1FFFFu) * DIM + sub * 4);
            float v = valid ? __uint_as_float(r.y) : 0.f;
            ax0 += v * e.x; ay0 += v * e.y; az0 += v * e.z; aw0 += v * e.w;
        }

        ax0 += ax1 + ax2 + ax3; ay0 += ay1 + ay2 + ay3;
        az0 += az1 + az2 + az3; aw0 += aw1 + aw2 + aw3;
        ax0 += __shfl_xor(ax0, 16, 64); ay0 += __shfl_xor(ay0, 16, 64);
        az0 += __shfl_xor(az0, 16, 64); aw0 += __shfl_xor(aw0, 16, 64);
        ax0 += __shfl_xor(ax0, 32, 64); ay0 += __shfl_xor(ay0, 32, 64);
        az0 += __shfl_xor(az0, 32, 64); aw0 += __shfl_xor(aw0, 32, 64);

        if (grp == 0 && bucket < nb) {
            float4 res = make_float4(ax0, ay0, az0, aw0);
            *(float4*)(out + (size_t)bucket * DIM + sub * 4) = res;
        }
    }
}

// rescan: reapply edges of overflowed partitions via atomics (normally no-op)
__global__ void pass3_rescan(const int* __restrict__ rows,
                             const int* __restrict__ cols,
                             const float* __restrict__ vals,
                             const float* __restrict__ user_emb,
                             const float* __restrict__ entity_emb,
                             const int* __restrict__ ovfcnt,
                             const unsigned char* __restrict__ ovfflag,
                             float* __restrict__ out, int ne, int nnz) {
    if (*ovfcnt == 0) return;
    for (int i = blockIdx.x * blockDim.x + threadIdx.x; i < nnz;
         i += gridDim.x * blockDim.x) {
        int c = cols[i];
        int r = rows[i];
        float v = vals[i];
        if (ovfflag[c >> PBITS]) {
            const float* src = user_emb + (size_t)r * DIM;
            float* dst = out + (size_t)c * DIM;
            for (int d = 0; d < DIM; ++d) atomicAdd(&dst[d], v * src[d]);
        }
        int b2 = ne + r;
        if (ovfflag[b2 >> PBITS]) {
            const float* src = entity_emb + (size_t)c * DIM;
            float* dst = out + (size_t)b2 * DIM;
            for (int d = 0; d < DIM; ++d) atomicAdd(&dst[d], v * src[d]);
        }
    }
}

extern "C" void kernel_launch(void* const* d_in, const int* in_sizes, int n_in,
                              void* d_out, int out_size, void* d_ws, size_t ws_size,
                              hipStream_t stream) {
    const float* user_emb   = (const float*)d_in[0];  // [n_users, 64]
    const float* entity_emb = (const float*)d_in[1];  // [n_entities, 64]
    const int*   rows       = (const int*)d_in[2];
    const int*   cols       = (const int*)d_in[3];
    const float* vals       = (const float*)d_in[4];
    int nnz = in_sizes[2];
    int nu  = in_sizes[0] / DIM;   // 100000
    int ne  = in_sizes[1] / DIM;   // 50000
    int nb  = ne + nu;             // 150000 buckets
    int npart = (nb + PART_BUCKETS - 1) >> PBITS;   // 2344
    int npeC  = (ne + PART_BUCKETS - 1) >> PBITS;   // 782 (entity + straddle)

    float* out = (float*)d_out;

    // ws layout: cnt[npart] int | ovfcnt int | ovfflag[npart] bytes | pad | payload
    size_t meta_bytes = (size_t)npart * 4 + 4 + (size_t)npart;
    size_t pay_off = (meta_bytes + 15) & ~(size_t)15;
    size_t nslots = (size_t)npeC * CAPE + (size_t)(npart - npeC) * CAPU;
    size_t need = pay_off + nslots * 8;
    long long avg_e = (long long)nnz * PART_BUCKETS / (ne > 0 ? ne : 1);
    long long avg_u = (long long)nnz * PART_BUCKETS / (nu > 0 ? nu : 1);

    if (ws_size < need || npart > NPART_MAX || nu > 131072 || ne > 131072 ||
        avg_e > 2700 || avg_u > 1500) {
        float* entity_agg = out;
        float* user_agg   = out + (size_t)ne * DIM;
        hipMemsetAsync(d_out, 0, (size_t)out_size * sizeof(float), stream);
        long long total = (long long)nnz * DIM;
        int block = 256;
        long long grid = (total + block - 1) / block;
        coo_scatter_kernel<<<(int)grid, block, 0, stream>>>(
            user_emb, entity_emb, rows, cols, vals, entity_agg, user_agg, nnz);
        return;
    }

    int*           cnt     = (int*)d_ws;
    int*           ovfcnt  = cnt + npart;
    unsigned char* ovfflag = (unsigned char*)(ovfcnt + 1);
    uint2*         payload = (uint2*)((char*)d_ws + pay_off);

    hipMemsetAsync(d_ws, 0, meta_bytes, stream);

    int g1 = (nnz + EPB - 1) / EPB;
    pass1_part<<<g1, 1024, 0, stream>>>(rows, cols, vals, cnt, payload, ne, nnz, npart, npeC);
    sort_agg<<<npart, 256, 0, stream>>>(user_emb, entity_emb, payload, cnt,
                                        ovfcnt, ovfflag, out, nb, npeC);
    pass3_rescan<<<512, 256, 0, stream>>>(rows, cols, vals, user_emb, entity_emb,
                                          ovfcnt, ovfflag, out, ne, nnz);
}